// Round 10
// baseline (62.356 us; speedup 1.0000x reference)
//
#include <hip/hip_runtime.h>

// Problem constants (from reference setup_inputs)
constexpr int B_   = 2;
constexpr int CIN  = 64;
constexpr int N    = 128;
constexpr int T    = 24;
constexpr int HID  = 64;
constexpr int COUT = 64;
constexpr int NT   = N * T;            // 3072
constexpr int ROWS = B_ * N * T;       // 6144
constexpr int BT   = B_ * T;           // 48
constexpr int MLP_BLOCKS = ROWS / 4;   // 1536
constexpr int TRS_BLOCKS = B_ * N;     // 256

typedef __attribute__((ext_vector_type(8))) short short8;  // 8 bf16 = MFMA A/B frag
typedef __attribute__((ext_vector_type(4))) float f32x4;

// float -> bf16 bits, round-to-nearest-even
__device__ inline unsigned short f2bf(float f) {
    unsigned u = __float_as_uint(f);
    return (unsigned short)((u + 0x7FFFu + ((u >> 16) & 1u)) >> 16);
}

// ---------------------------------------------------------------------------
// k_prep: IDENTICAL to R9 (control for the slope experiment).
// ---------------------------------------------------------------------------
__global__ __launch_bounds__(256) void k_prep(
    const float* __restrict__ x,
    const float* __restrict__ att,
    const float* __restrict__ W1,
    const float* __restrict__ b1,
    const float* __restrict__ W2,
    const float* __restrict__ b2,
    float* __restrict__ mvb2,
    float* __restrict__ mh,
    unsigned int* __restrict__ attT32,
    float* __restrict__ asum_g)
{
    const int tid = threadIdx.x;

    if (blockIdx.x < MLP_BLOCKS) {
        __shared__ float xs[4][64];
        __shared__ float hs[4][64];

        const int r   = tid >> 6;
        const int k   = tid & 63;
        const int row = blockIdx.x * 4 + r;
        const int b   = row / NT;
        const int nt  = row - b * NT;

        xs[r][k] = x[(size_t)b * CIN * NT + (size_t)k * NT + nt];
        __syncthreads();

        float h = b1[k];
#pragma unroll
        for (int c = 0; c < CIN; ++c) h += xs[r][c] * W1[c * HID + k];
        hs[r][k] = h;
        __syncthreads();

        float mv = 0.f, mhv = 0.f;
#pragma unroll
        for (int q = 0; q < HID; ++q) {
            const float hq = hs[r][q];
            mv  += hq * W2[q * COUT + k];
            mhv += hq * W2[(HID + q) * COUT + k];
        }
        const int n  = nt / T;
        const int t  = nt - n * T;
        const int bt = b * T + t;
        const size_t o = ((size_t)bt * N + n) * COUT + k;   // lane=k contiguous
        mvb2[o] = mv + b2[k];
        mh[o]   = mhv;
    } else {
        __shared__ float ts[N][T + 1];
        __shared__ float psum[T][8];

        const int tb = blockIdx.x - MLP_BLOCKS;
        const int b  = tb >> 7;
        const int i  = tb & 127;

        const float* ab = att + ((size_t)b * N + i) * NT;
#pragma unroll
        for (int u = 0; u < 12; ++u) {
            const int idx = tid + 256 * u;
            const int j   = idx / T;
            const int t   = idx - j * T;
            ts[j][t] = ab[idx];
        }
        __syncthreads();

#pragma unroll
        for (int u = 0; u < 6; ++u) {
            const int e2 = tid + 256 * u;
            const int t  = e2 >> 6;
            const int jp = e2 & 63;
            const int j  = jp * 2;
            const unsigned pk = (unsigned)f2bf(ts[j][t])
                              | ((unsigned)f2bf(ts[j + 1][t]) << 16);
            attT32[((size_t)(b * T + t) * N + i) * 64 + jp] = pk;
        }
        if (tid < 192) {
            const int t = tid >> 3;
            const int p = tid & 7;
            float s = 0.f;
#pragma unroll
            for (int q = 0; q < 16; ++q) s += ts[p * 16 + q][t];
            psum[t][p] = s;
        }
        __syncthreads();
        if (tid < T) {
            float s = 0.f;
#pragma unroll
            for (int p = 0; p < 8; ++p) s += psum[tid][p];
            asum_g[(size_t)(b * T + tid) * N + i] = s;
        }
    }
}

// ---------------------------------------------------------------------------
// k_att: IDENTICAL to R9.
// ---------------------------------------------------------------------------
__global__ __launch_bounds__(256) void k_att(
    const unsigned short* __restrict__ attTb,
    const float* __restrict__ mh,
    const float* __restrict__ mvb2,
    const float* __restrict__ asum_g,
    float* __restrict__ out)
{
    __shared__ unsigned short mhs[COUT][136];   // 17.4 KB, padded rows

    const int blk   = blockIdx.x;
    const int itile = blk & 7;
    const int bt    = blk >> 3;
    const int b     = bt / T;
    const int t     = bt - b * T;

    const int tid  = threadIdx.x;
    const int w    = tid >> 6;
    const int lane = tid & 63;
    const int c16  = lane & 15;
    const int q4   = lane >> 4;
    const int cc   = w * 16 + c16;

    {
        const float* src = mh + (size_t)bt * N * COUT;
#pragma unroll
        for (int u = 0; u < 32; ++u) {
            const int v = tid + 256 * u;      // j*64 + c
            const int j = v >> 6;
            const int c = v & 63;
            mhs[c][j] = f2bf(src[v]);
        }
    }
    __syncthreads();

    const unsigned short* arow = attTb + ((size_t)bt * N + itile * 16 + c16) * N;

    f32x4 acc = {0.f, 0.f, 0.f, 0.f};
#pragma unroll
    for (int ks = 0; ks < 4; ++ks) {
        const short8 a  = *(const short8*)(arow + ks * 32 + q4 * 8);
        const short8 bb = *(const short8*)(&mhs[cc][ks * 32 + q4 * 8]);
        acc = __builtin_amdgcn_mfma_f32_16x16x32_bf16(a, bb, acc, 0, 0, 0);
    }

    const int il0 = itile * 16 + q4 * 4;

    const f32x4 as4 = *(const f32x4*)(asum_g + (size_t)bt * N + il0);

    float* ob = out + (((size_t)b * COUT + cc) * N + il0) * T + t;
#pragma unroll
    for (int e = 0; e < 4; ++e) {
        const float mb = mvb2[((size_t)bt * N + il0 + e) * COUT + cc];
        ob[e * T] = acc[e] + as4[e] * mb;
    }
}

// ---------------------------------------------------------------------------
// R10 = R9 + slope experiment on k_prep: real prep, then 3 dummy preps
// writing to scratch. dur(R10) - dur(R9) = 3 * (K_prep + F_launch).
// ---------------------------------------------------------------------------
extern "C" void kernel_launch(void* const* d_in, const int* in_sizes, int n_in,
                              void* d_out, int out_size, void* d_ws, size_t ws_size,
                              hipStream_t stream)
{
    const float* x   = (const float*)d_in[0];
    const float* att = (const float*)d_in[1];
    const float* W1  = (const float*)d_in[2];
    const float* b1  = (const float*)d_in[3];
    const float* W2  = (const float*)d_in[4];
    const float* b2  = (const float*)d_in[5];
    float* out = (float*)d_out;

    // Workspace layout (bytes), all 16B-aligned — identical to R9:
    char* ws = (char*)d_ws;
    float*          mvb2   = (float*)ws;                           // 1,572,864 B
    float*          mh     = (float*)(ws + 1572864);               // 1,572,864 B
    float*          asum_g = (float*)(ws + 3145728);               //    24,576 B
    unsigned int*   attT32 = (unsigned int*)(ws + 3170304);        // 1,572,864 B
    const unsigned short* attTb = (const unsigned short*)attT32;

    // Dummy region for slope-experiment writes (ws + 8 MiB onward).
    char* dmy = ws + 8388608;
    float*        mvb2_d   = (float*)dmy;                          // 1,572,864 B
    float*        mh_d     = (float*)(dmy + 1572864);              // 1,572,864 B
    float*        asum_d   = (float*)(dmy + 3145728);              //    24,576 B
    unsigned int* attT32_d = (unsigned int*)(dmy + 3170304);       // 1,572,864 B

    // Real prep first (produces the outputs k_att consumes).
    k_prep<<<MLP_BLOCKS + TRS_BLOCKS, 256, 0, stream>>>(
        x, att, W1, b1, W2, b2, mvb2, mh, attT32, asum_g);
    // 3 dummy replicas (identical reads, scratch writes) — slope probe.
    k_prep<<<MLP_BLOCKS + TRS_BLOCKS, 256, 0, stream>>>(
        x, att, W1, b1, W2, b2, mvb2_d, mh_d, attT32_d, asum_d);
    k_prep<<<MLP_BLOCKS + TRS_BLOCKS, 256, 0, stream>>>(
        x, att, W1, b1, W2, b2, mvb2_d, mh_d, attT32_d, asum_d);
    k_prep<<<MLP_BLOCKS + TRS_BLOCKS, 256, 0, stream>>>(
        x, att, W1, b1, W2, b2, mvb2_d, mh_d, attT32_d, asum_d);

    k_att<<<BT * 8, 256, 0, stream>>>(attTb, mh, mvb2, asum_g, out);
}

// Round 11
// 25.832 us; speedup vs baseline: 2.4139x; 2.4139x over previous
//
#include <hip/hip_runtime.h>

// Problem constants (from reference setup_inputs)
constexpr int B_   = 2;
constexpr int CIN  = 64;
constexpr int N    = 128;
constexpr int T    = 24;
constexpr int HID  = 64;
constexpr int COUT = 64;
constexpr int NT   = N * T;            // 3072
constexpr int BT   = B_ * T;           // 48
constexpr int MLP_BLOCKS = BT * 8;     // 384 (16 n-rows each)
constexpr int TRS_BLOCKS = B_ * N;     // 256

typedef __attribute__((ext_vector_type(8))) short short8;  // 8 bf16 = MFMA A/B frag
typedef __attribute__((ext_vector_type(4))) float f32x4;

// float -> bf16 bits, round-to-nearest-even
__device__ inline unsigned short f2bf(float f) {
    unsigned u = __float_as_uint(f);
    return (unsigned short)((u + 0x7FFFu + ((u >> 16) & 1u)) >> 16);
}

// ---------------------------------------------------------------------------
// k_prep: MLP blocks [0,384) + att transpose/sum blocks [384,640).
//  MLP block = (bt, n-chunk of 16). Per row (R1-anchored math):
//    h = x_row@W1+b1 ; mv = h@W2[:HID]+b2 ; mh = h@W2[HID:]
//  Rows collect in LDS; block then stores TRANSPOSED layouts (what R6's
//  anchored k_att wants) with dword+ stores in 32-64B runs:
//    mhT32 [bt][c][n/2]  u32-packed bf16 pairs  (8B/thread, 32B runs)
//    mvb2T [bt][c][n]    f32                    (16B/thread, 64B runs)
//  att section: R6-validated verbatim.
// ---------------------------------------------------------------------------
__global__ __launch_bounds__(256) void k_prep(
    const float* __restrict__ x,
    const float* __restrict__ att,
    const float* __restrict__ W1,
    const float* __restrict__ b1,
    const float* __restrict__ W2,
    const float* __restrict__ b2,
    float* __restrict__ mvb2T,
    unsigned int* __restrict__ mhT32,
    unsigned int* __restrict__ attT32,
    float* __restrict__ asum_g)
{
    const int tid = threadIdx.x;

    if (blockIdx.x < MLP_BLOCKS) {
        __shared__ float xs[4][64];
        __shared__ float hs[4][64];
        __shared__ float mvs[16][65];
        __shared__ float mhs[16][65];

        const int blk = blockIdx.x;
        const int bt  = blk >> 3;           // b*T + t
        const int n0  = (blk & 7) * 16;
        const int b   = bt / T;
        const int t   = bt - b * T;

        const int w = tid >> 6;             // wave
        const int k = tid & 63;             // lane = channel

        for (int it = 0; it < 4; ++it) {
            const int rl = w * 4 + it;      // local row 0..15
            const int n  = n0 + rl;
            const int nt = n * T + t;

            xs[w][k] = x[(size_t)b * CIN * NT + (size_t)k * NT + nt];
            __syncthreads();

            float h = b1[k];
#pragma unroll
            for (int c = 0; c < CIN; ++c) h += xs[w][c] * W1[c * HID + k];
            hs[w][k] = h;
            __syncthreads();

            float mv = 0.f, mhv = 0.f;
#pragma unroll
            for (int q = 0; q < HID; ++q) {
                const float hq = hs[w][q];
                mv  += hq * W2[q * COUT + k];
                mhv += hq * W2[(HID + q) * COUT + k];
            }
            mvs[rl][k] = mv + b2[k];
            mhs[rl][k] = mhv;
            __syncthreads();
        }

        // Transposed stores.
        // mhT: thread -> c = tid>>2, pair p0 = (tid&3)*2 ; 8B store, 32B runs.
        {
            const int c  = tid >> 2;
            const int p0 = (tid & 3) * 2;   // covers n_loc 2p0..2p0+3
            uint2 pk;
            pk.x = (unsigned)f2bf(mhs[p0 * 2 + 0][c])
                 | ((unsigned)f2bf(mhs[p0 * 2 + 1][c]) << 16);
            pk.y = (unsigned)f2bf(mhs[p0 * 2 + 2][c])
                 | ((unsigned)f2bf(mhs[p0 * 2 + 3][c]) << 16);
            *(uint2*)&mhT32[((size_t)bt * COUT + c) * 64 + (n0 >> 1) + p0] = pk;
        }
        // mvb2T: thread -> c = tid>>2, n_off = (tid&3)*4 ; 16B store, 64B runs.
        {
            const int c  = tid >> 2;
            const int nf = (tid & 3) * 4;
            f32x4 v;
            v[0] = mvs[nf + 0][c];
            v[1] = mvs[nf + 1][c];
            v[2] = mvs[nf + 2][c];
            v[3] = mvs[nf + 3][c];
            *(f32x4*)&mvb2T[((size_t)bt * COUT + c) * N + n0 + nf] = v;
        }
    } else {
        __shared__ float ts[N][T + 1];
        __shared__ float psum[T][8];

        const int tb = blockIdx.x - MLP_BLOCKS;
        const int b  = tb >> 7;
        const int i  = tb & 127;

        const float* ab = att + ((size_t)b * N + i) * NT;
#pragma unroll
        for (int u = 0; u < 12; ++u) {
            const int idx = tid + 256 * u;
            const int j   = idx / T;
            const int t   = idx - j * T;
            ts[j][t] = ab[idx];
        }
        __syncthreads();

#pragma unroll
        for (int u = 0; u < 6; ++u) {
            const int e2 = tid + 256 * u;
            const int t  = e2 >> 6;
            const int jp = e2 & 63;
            const int j  = jp * 2;
            const unsigned pk = (unsigned)f2bf(ts[j][t])
                              | ((unsigned)f2bf(ts[j + 1][t]) << 16);
            attT32[((size_t)(b * T + t) * N + i) * 64 + jp] = pk;
        }
        if (tid < 192) {
            const int t = tid >> 3;
            const int p = tid & 7;
            float s = 0.f;
#pragma unroll
            for (int q = 0; q < 16; ++q) s += ts[p * 16 + q][t];
            psum[t][p] = s;
        }
        __syncthreads();
        if (tid < T) {
            float s = 0.f;
#pragma unroll
            for (int p = 0; p < 8; ++p) s += psum[tid][p];
            asum_g[(size_t)(b * T + tid) * N + i] = s;
        }
    }
}

// ---------------------------------------------------------------------------
// k_att: IDENTICAL to R6 (4.9 us incl launch, slope-anchored).
// ---------------------------------------------------------------------------
__global__ __launch_bounds__(256) void k_att(
    const unsigned short* __restrict__ attTb,
    const unsigned short* __restrict__ mhT,
    const float* __restrict__ mvb2T,
    const float* __restrict__ asum_g,
    float* __restrict__ out)
{
    const int blk   = blockIdx.x;
    const int itile = blk & 7;
    const int bt    = blk >> 3;
    const int b     = bt / T;
    const int t     = bt - b * T;

    const int tid  = threadIdx.x;
    const int w    = tid >> 6;
    const int lane = tid & 63;
    const int c16  = lane & 15;
    const int q4   = lane >> 4;
    const int n0   = w * 16;

    const unsigned short* arow = attTb + ((size_t)bt * N + itile * 16 + c16) * N;
    const unsigned short* brow = mhT   + ((size_t)bt * COUT + n0 + c16) * N;

    f32x4 acc = {0.f, 0.f, 0.f, 0.f};
#pragma unroll
    for (int ks = 0; ks < 4; ++ks) {
        const short8 a  = *(const short8*)(arow + ks * 32 + q4 * 8);
        const short8 bb = *(const short8*)(brow + ks * 32 + q4 * 8);
        acc = __builtin_amdgcn_mfma_f32_16x16x32_bf16(a, bb, acc, 0, 0, 0);
    }

    const int il0 = itile * 16 + q4 * 4;
    const int cc  = n0 + c16;

    const f32x4 mb  = *(const f32x4*)(mvb2T + ((size_t)bt * COUT + cc) * N + il0);
    const f32x4 as4 = *(const f32x4*)(asum_g + (size_t)bt * N + il0);

    float* ob = out + (((size_t)b * COUT + cc) * N + il0) * T + t;
#pragma unroll
    for (int e = 0; e < 4; ++e) {
        ob[e * T] = acc[e] + as4[e] * mb[e];
    }
}

// ---------------------------------------------------------------------------
extern "C" void kernel_launch(void* const* d_in, const int* in_sizes, int n_in,
                              void* d_out, int out_size, void* d_ws, size_t ws_size,
                              hipStream_t stream)
{
    const float* x   = (const float*)d_in[0];
    const float* att = (const float*)d_in[1];
    const float* W1  = (const float*)d_in[2];
    const float* b1  = (const float*)d_in[3];
    const float* W2  = (const float*)d_in[4];
    const float* b2  = (const float*)d_in[5];
    float* out = (float*)d_out;

    // Workspace layout (bytes), all 16B-aligned:
    char* ws = (char*)d_ws;
    float*        mvb2T  = (float*)ws;                         // 1,572,864 B
    float*        asum_g = (float*)(ws + 1572864);             //    24,576 B
    unsigned int* mhT32  = (unsigned int*)(ws + 1597440);      //   786,432 B
    unsigned int* attT32 = (unsigned int*)(ws + 2383872);      // 1,572,864 B

    k_prep<<<MLP_BLOCKS + TRS_BLOCKS, 256, 0, stream>>>(
        x, att, W1, b1, W2, b2, mvb2T, mhT32, attT32, asum_g);
    k_att<<<BT * 8, 256, 0, stream>>>((const unsigned short*)attT32,
                                      (const unsigned short*)mhT32,
                                      mvb2T, asum_g, out);
}